// Round 8
// baseline (1548.512 us; speedup 1.0000x reference)
//
#include <hip/hip_runtime.h>

#define D 128
#define TM 16
#define TG 32   // gemm node tile (32 KB LDS total -> 5 blocks/CU)

// ---------------- CSR build ----------------

__global__ void hist_kernel(const int* __restrict__ dst, int* __restrict__ deg, int E) {
    int i = blockIdx.x * blockDim.x + threadIdx.x;
    if (i < E) atomicAdd(&deg[dst[i]], 1);
}

__global__ void scan1_kernel(const int* __restrict__ deg, int* __restrict__ local_excl,
                             int* __restrict__ blocksum, int n) {
    __shared__ int tmp[1024];
    int i = blockIdx.x * 1024 + threadIdx.x;
    int v = (i < n) ? deg[i] : 0;
    tmp[threadIdx.x] = v;
    __syncthreads();
    for (int off = 1; off < 1024; off <<= 1) {
        int t = 0;
        if (threadIdx.x >= off) t = tmp[threadIdx.x - off];
        __syncthreads();
        if (threadIdx.x >= off) tmp[threadIdx.x] += t;
        __syncthreads();
    }
    int incl = tmp[threadIdx.x];
    if (i < n) local_excl[i] = incl - v;
    if (threadIdx.x == 1023) blocksum[blockIdx.x] = tmp[1023];
}

__global__ void scan2_kernel(int* __restrict__ blocksum, int nb) {
    __shared__ int tmp[1024];
    int v = (threadIdx.x < nb) ? blocksum[threadIdx.x] : 0;
    tmp[threadIdx.x] = v;
    __syncthreads();
    for (int off = 1; off < 1024; off <<= 1) {
        int t = 0;
        if (threadIdx.x >= off) t = tmp[threadIdx.x - off];
        __syncthreads();
        if (threadIdx.x >= off) tmp[threadIdx.x] += t;
        __syncthreads();
    }
    if (threadIdx.x < nb) blocksum[threadIdx.x] = tmp[threadIdx.x] - v;  // exclusive
}

__global__ void scan3_kernel(const int* __restrict__ deg, const int* __restrict__ local_excl,
                             const int* __restrict__ blocksum, int* __restrict__ row_start,
                             int* __restrict__ cursor, float* __restrict__ inv_deg,
                             int n, int n_edges) {
    int i = blockIdx.x * 1024 + threadIdx.x;
    if (i < n) {
        int rs = local_excl[i] + blocksum[blockIdx.x];
        row_start[i] = rs;
        cursor[i]    = rs;
        inv_deg[i]   = 1.0f / fmaxf((float)deg[i], 1.0f);
    }
    if (i == 0) row_start[n] = n_edges;
}

// csr[] holds BYTE offsets of the source row (src * D * 4).
__global__ void scatter_kernel(const int* __restrict__ src, const int* __restrict__ dst,
                               int* __restrict__ cursor, int* __restrict__ csr, int E) {
    int i = blockIdx.x * blockDim.x + threadIdx.x;
    if (i < E) {
        int d = dst[i];
        int p = atomicAdd(&cursor[d], 1);
        csr[p] = src[i] << 9;   // * 512 bytes per row
    }
}

// ---------------- weight transpose (W[l][f][k] -> Wt[l][k][f]) ----------------

__global__ void transpose_w(const float* __restrict__ Wl, const float* __restrict__ Wr,
                            float* __restrict__ Wlt, float* __restrict__ Wrt, int total) {
    int i = blockIdx.x * blockDim.x + threadIdx.x;
    if (i < total) {
        int l = i >> 14;
        int r = i & 16383;
        int f = r >> 7;
        int k = r & 127;
        int o = (l << 14) + (k << 7) + f;
        Wlt[o] = Wl[i];
        Wrt[o] = Wr[i];
    }
}

// ---------------- gather-mean kernel (no LDS) ----------------
// One wave per node (4 nodes/wave sequential). Wave splits into two 32-lane
// halves walking alternate edges, 4-deep float4 pipeline per half = 8 row
// loads in flight/wave. ~125 us/layer ~= gather-BW floor through L2/L3.
__global__ void agg_kernel(const float* __restrict__ xin, float* __restrict__ agg,
                           const int* __restrict__ row_start, const int* __restrict__ csr,
                           const float* __restrict__ inv_deg, int n_nodes) {
    int tid  = threadIdx.x;
    int lane = tid & 63;
    int w    = tid >> 6;      // wave 0..3
    int h    = lane >> 5;     // half 0/1
    int sl   = lane & 31;
    const char* xbase = (const char*)xin;
    int laneoff = sl * 16;
    int block0 = blockIdx.x * TM;

    for (int t = 0; t < 4; ++t) {
        int n = block0 + w * 4 + t;
        if (n >= n_nodes) return;
        int e0 = row_start[n];
        int e1 = row_start[n + 1];
        float idg = inv_deg[n];
        float4 s0 = {0,0,0,0}, s1 = {0,0,0,0}, s2 = {0,0,0,0}, s3 = {0,0,0,0};

        int e = e0 + h;
        for (; e + 6 < e1; e += 8) {
            int o0i = csr[e], o1i = csr[e + 2], o2i = csr[e + 4], o3i = csr[e + 6];
            float4 v0 = *(const float4*)(xbase + (size_t)(o0i + laneoff));
            float4 v1 = *(const float4*)(xbase + (size_t)(o1i + laneoff));
            float4 v2 = *(const float4*)(xbase + (size_t)(o2i + laneoff));
            float4 v3 = *(const float4*)(xbase + (size_t)(o3i + laneoff));
            s0.x += v0.x; s0.y += v0.y; s0.z += v0.z; s0.w += v0.w;
            s1.x += v1.x; s1.y += v1.y; s1.z += v1.z; s1.w += v1.w;
            s2.x += v2.x; s2.y += v2.y; s2.z += v2.z; s2.w += v2.w;
            s3.x += v3.x; s3.y += v3.y; s3.z += v3.z; s3.w += v3.w;
        }
        for (; e < e1; e += 2) {
            int o0i = csr[e];
            float4 v0 = *(const float4*)(xbase + (size_t)(o0i + laneoff));
            s0.x += v0.x; s0.y += v0.y; s0.z += v0.z; s0.w += v0.w;
        }

        float4 s;
        s.x = (s0.x + s1.x) + (s2.x + s3.x);
        s.y = (s0.y + s1.y) + (s2.y + s3.y);
        s.z = (s0.z + s1.z) + (s2.z + s3.z);
        s.w = (s0.w + s1.w) + (s2.w + s3.w);
        s.x += __shfl_down(s.x, 32);
        s.y += __shfl_down(s.y, 32);
        s.z += __shfl_down(s.z, 32);
        s.w += __shfl_down(s.w, 32);
        if (h == 0) {
            float4 r;
            r.x = s.x * idg; r.y = s.y * idg; r.z = s.z * idg; r.w = s.w * idg;
            ((float4*)(agg + (size_t)n * D))[sl] = r;
        }
    }
}

// ---------------- dual-GEMM + bias + relu kernel ----------------
// 32-node tile, thread = 2 nodes x 8 features, k-step 2.
// Per k-step: 64 fmacs vs 8 VMEM f4 (weights) + 4 LDS b64 (A/X) -> ~85% of
// issue slots are FMA (r7 at 4-feature threads was ~60%, measured 26% FMA
// cycle density / 41 TF). LB(256,2) caps VGPR at ~128 so the 32-reg weight
// set + 16-reg acc live legitimately (r7's default cap of 60 forced
// re-loads; r3/r4: tighter bounds spill to scratch).
#define FMA4(ACC, W, S) ACC.x += W.x * (S); ACC.y += W.y * (S); \
                        ACC.z += W.z * (S); ACC.w += W.w * (S);

__launch_bounds__(256, 2)
__global__ void gemm_kernel(const float* __restrict__ agg, const float* __restrict__ xin,
                            float* __restrict__ xout,
                            const float* __restrict__ Wlt, const float* __restrict__ Wrt,
                            const float* __restrict__ bl, int n_nodes) {
    __shared__ __align__(16) float A[TG][D];
    __shared__ __align__(16) float X[TG][D];
    int tid = threadIdx.x;
    int block0 = blockIdx.x * TG;

    // stage 32 rows of agg and x (1024 float4 each -> 4 per thread each)
    const float4* agg4 = (const float4*)(agg + (size_t)block0 * D);
    const float4* x4   = (const float4*)(xin + (size_t)block0 * D);
    float4* A4 = (float4*)A;
    float4* X4 = (float4*)X;
    int limit4 = (n_nodes - block0) * 32;   // float4s available in this tile
    #pragma unroll
    for (int t = 0; t < 4; ++t) {
        int i = t * 256 + tid;
        float4 za = {0,0,0,0}, zx = {0,0,0,0};
        if (i < limit4) { za = agg4[i]; zx = x4[i]; }
        A4[i] = za;
        X4[i] = zx;
    }
    __syncthreads();

    int tf2 = (tid & 15) * 2;   // f4 index: features [tf2*4, tf2*4+8)
    int tn  = tid >> 4;         // node pair 0..15
    int n0i = tn * 2, n1i = n0i + 1;
    const float4* Wlt4 = (const float4*)Wlt;
    const float4* Wrt4 = (const float4*)Wrt;
    float4 acc00 = ((const float4*)bl)[tf2];
    float4 acc01 = ((const float4*)bl)[tf2 + 1];
    float4 acc10 = acc00, acc11 = acc01;

    const float* Arow0 = A[n0i];
    const float* Arow1 = A[n1i];
    const float* Xrow0 = X[n0i];
    const float* Xrow1 = X[n1i];

    for (int k = 0; k < D; k += 2) {
        float4 wl00 = Wlt4[(k + 0) * 32 + tf2];
        float4 wl01 = Wlt4[(k + 0) * 32 + tf2 + 1];
        float4 wl10 = Wlt4[(k + 1) * 32 + tf2];
        float4 wl11 = Wlt4[(k + 1) * 32 + tf2 + 1];
        float4 wr00 = Wrt4[(k + 0) * 32 + tf2];
        float4 wr01 = Wrt4[(k + 0) * 32 + tf2 + 1];
        float4 wr10 = Wrt4[(k + 1) * 32 + tf2];
        float4 wr11 = Wrt4[(k + 1) * 32 + tf2 + 1];
        float2 a0 = *(const float2*)&Arow0[k];
        float2 a1 = *(const float2*)&Arow1[k];
        float2 x0 = *(const float2*)&Xrow0[k];
        float2 x1 = *(const float2*)&Xrow1[k];

        FMA4(acc00, wl00, a0.x) FMA4(acc00, wl10, a0.y)
        FMA4(acc00, wr00, x0.x) FMA4(acc00, wr10, x0.y)
        FMA4(acc01, wl01, a0.x) FMA4(acc01, wl11, a0.y)
        FMA4(acc01, wr01, x0.x) FMA4(acc01, wr11, x0.y)
        FMA4(acc10, wl00, a1.x) FMA4(acc10, wl10, a1.y)
        FMA4(acc10, wr00, x1.x) FMA4(acc10, wr10, x1.y)
        FMA4(acc11, wl01, a1.x) FMA4(acc11, wl11, a1.y)
        FMA4(acc11, wr01, x1.x) FMA4(acc11, wr11, x1.y)
    }

    int n0 = block0 + n0i, n1 = block0 + n1i;
    if (n0 < n_nodes) {
        float4 r0, r1;
        r0.x = fmaxf(acc00.x, 0.f); r0.y = fmaxf(acc00.y, 0.f);
        r0.z = fmaxf(acc00.z, 0.f); r0.w = fmaxf(acc00.w, 0.f);
        r1.x = fmaxf(acc01.x, 0.f); r1.y = fmaxf(acc01.y, 0.f);
        r1.z = fmaxf(acc01.z, 0.f); r1.w = fmaxf(acc01.w, 0.f);
        ((float4*)xout)[(size_t)n0 * 32 + tf2]     = r0;
        ((float4*)xout)[(size_t)n0 * 32 + tf2 + 1] = r1;
    }
    if (n1 < n_nodes) {
        float4 r0, r1;
        r0.x = fmaxf(acc10.x, 0.f); r0.y = fmaxf(acc10.y, 0.f);
        r0.z = fmaxf(acc10.z, 0.f); r0.w = fmaxf(acc10.w, 0.f);
        r1.x = fmaxf(acc11.x, 0.f); r1.y = fmaxf(acc11.y, 0.f);
        r1.z = fmaxf(acc11.z, 0.f); r1.w = fmaxf(acc11.w, 0.f);
        ((float4*)xout)[(size_t)n1 * 32 + tf2]     = r0;
        ((float4*)xout)[(size_t)n1 * 32 + tf2 + 1] = r1;
    }
}

extern "C" void kernel_launch(void* const* d_in, const int* in_sizes, int n_in,
                              void* d_out, int out_size, void* d_ws, size_t ws_size,
                              hipStream_t stream) {
    const float* x  = (const float*)d_in[0];
    const int*  edge = (const int*)d_in[1];
    const float* Wl = (const float*)d_in[2];
    const float* bl = (const float*)d_in[3];
    const float* Wr = (const float*)d_in[4];

    int N = in_sizes[0] / D;
    int E = in_sizes[1] / 2;
    int L = in_sizes[3] / D;
    const int* srcp = edge;
    const int* dstp = edge + E;

    char* w = (char*)d_ws;
    auto alloc = [&](size_t bytes) {
        char* p = w;
        w += (bytes + 255) & ~(size_t)255;
        return p;
    };
    int*   deg       = (int*)alloc((size_t)N * 4);
    int*   local_ex  = (int*)alloc((size_t)N * 4);
    int*   row_start = (int*)alloc((size_t)(N + 1) * 4);
    int*   cursor    = (int*)alloc((size_t)N * 4);
    int*   csr       = (int*)alloc((size_t)E * 4);
    float* invdeg    = (float*)alloc((size_t)N * 4);
    int*   blocksum  = (int*)alloc((size_t)1024 * 4);
    float* wlt       = (float*)alloc((size_t)L * D * D * 4);
    float* wrt       = (float*)alloc((size_t)L * D * D * 4);
    float* buf0      = (float*)alloc((size_t)N * D * 4);
    float* aggbuf    = (float*)alloc((size_t)N * D * 4);

    int nb1 = (N + 1023) / 1024;
    hipMemsetAsync(deg, 0, (size_t)N * 4, stream);
    hist_kernel<<<(E + 255) / 256, 256, 0, stream>>>(dstp, deg, E);
    scan1_kernel<<<nb1, 1024, 0, stream>>>(deg, local_ex, blocksum, N);
    scan2_kernel<<<1, 1024, 0, stream>>>(blocksum, nb1);
    scan3_kernel<<<nb1, 1024, 0, stream>>>(deg, local_ex, blocksum, row_start,
                                           cursor, invdeg, N, E);
    scatter_kernel<<<(E + 255) / 256, 256, 0, stream>>>(srcp, dstp, cursor, csr, E);
    int tw = L * D * D;
    transpose_w<<<(tw + 255) / 256, 256, 0, stream>>>(Wl, Wr, wlt, wrt, tw);

    float* out = (float*)d_out;
    const float* cur = x;
    int nb_agg  = (N + TM - 1) / TM;
    int nb_gemm = (N + TG - 1) / TG;
    for (int l = 0; l < L; ++l) {
        float* o = (l & 1) ? out : buf0;
        if (l == L - 1) o = out;
        agg_kernel<<<nb_agg, 256, 0, stream>>>(cur, aggbuf, row_start, csr, invdeg, N);
        gemm_kernel<<<nb_gemm, 256, 0, stream>>>(aggbuf, cur, o,
                                                 wlt + (size_t)l * D * D,
                                                 wrt + (size_t)l * D * D,
                                                 bl + (size_t)l * D, N);
        cur = o;
    }
}

// Round 9
// 1343.626 us; speedup vs baseline: 1.1525x; 1.1525x over previous
//
#include <hip/hip_runtime.h>

#define D 128
#define TM 16
#define TG 32   // gemm node tile (32 KB LDS total -> 5 blocks/CU)

// ---------------- CSR build ----------------

__global__ void hist_kernel(const int* __restrict__ dst, int* __restrict__ deg, int E) {
    int i = blockIdx.x * blockDim.x + threadIdx.x;
    if (i < E) atomicAdd(&deg[dst[i]], 1);
}

__global__ void scan1_kernel(const int* __restrict__ deg, int* __restrict__ local_excl,
                             int* __restrict__ blocksum, int n) {
    __shared__ int tmp[1024];
    int i = blockIdx.x * 1024 + threadIdx.x;
    int v = (i < n) ? deg[i] : 0;
    tmp[threadIdx.x] = v;
    __syncthreads();
    for (int off = 1; off < 1024; off <<= 1) {
        int t = 0;
        if (threadIdx.x >= off) t = tmp[threadIdx.x - off];
        __syncthreads();
        if (threadIdx.x >= off) tmp[threadIdx.x] += t;
        __syncthreads();
    }
    int incl = tmp[threadIdx.x];
    if (i < n) local_excl[i] = incl - v;
    if (threadIdx.x == 1023) blocksum[blockIdx.x] = tmp[1023];
}

__global__ void scan2_kernel(int* __restrict__ blocksum, int nb) {
    __shared__ int tmp[1024];
    int v = (threadIdx.x < nb) ? blocksum[threadIdx.x] : 0;
    tmp[threadIdx.x] = v;
    __syncthreads();
    for (int off = 1; off < 1024; off <<= 1) {
        int t = 0;
        if (threadIdx.x >= off) t = tmp[threadIdx.x - off];
        __syncthreads();
        if (threadIdx.x >= off) tmp[threadIdx.x] += t;
        __syncthreads();
    }
    if (threadIdx.x < nb) blocksum[threadIdx.x] = tmp[threadIdx.x] - v;  // exclusive
}

__global__ void scan3_kernel(const int* __restrict__ deg, const int* __restrict__ local_excl,
                             const int* __restrict__ blocksum, int* __restrict__ row_start,
                             int* __restrict__ cursor, float* __restrict__ inv_deg,
                             int n, int n_edges) {
    int i = blockIdx.x * 1024 + threadIdx.x;
    if (i < n) {
        int rs = local_excl[i] + blocksum[blockIdx.x];
        row_start[i] = rs;
        cursor[i]    = rs;
        inv_deg[i]   = 1.0f / fmaxf((float)deg[i], 1.0f);
    }
    if (i == 0) row_start[n] = n_edges;
}

// csr[] holds BYTE offsets of the source row (src * D * 4).
__global__ void scatter_kernel(const int* __restrict__ src, const int* __restrict__ dst,
                               int* __restrict__ cursor, int* __restrict__ csr, int E) {
    int i = blockIdx.x * blockDim.x + threadIdx.x;
    if (i < E) {
        int d = dst[i];
        int p = atomicAdd(&cursor[d], 1);
        csr[p] = src[i] << 9;   // * 512 bytes per row
    }
}

// ---------------- weight transpose (W[l][f][k] -> Wt[l][k][f]) ----------------

__global__ void transpose_w(const float* __restrict__ Wl, const float* __restrict__ Wr,
                            float* __restrict__ Wlt, float* __restrict__ Wrt, int total) {
    int i = blockIdx.x * blockDim.x + threadIdx.x;
    if (i < total) {
        int l = i >> 14;
        int r = i & 16383;
        int f = r >> 7;
        int k = r & 127;
        int o = (l << 14) + (k << 7) + f;
        Wlt[o] = Wl[i];
        Wrt[o] = Wr[i];
    }
}

// ---------------- gather-mean kernel (no LDS) ----------------
// One wave per node (4 nodes/wave sequential). Wave splits into two 32-lane
// halves walking alternate edges, 4-deep float4 pipeline per half = 8 row
// loads in flight/wave. ~125 us/layer ~= gather-BW floor through L2/L3.
__global__ void agg_kernel(const float* __restrict__ xin, float* __restrict__ agg,
                           const int* __restrict__ row_start, const int* __restrict__ csr,
                           const float* __restrict__ inv_deg, int n_nodes) {
    int tid  = threadIdx.x;
    int lane = tid & 63;
    int w    = tid >> 6;      // wave 0..3
    int h    = lane >> 5;     // half 0/1
    int sl   = lane & 31;
    const char* xbase = (const char*)xin;
    int laneoff = sl * 16;
    int block0 = blockIdx.x * TM;

    for (int t = 0; t < 4; ++t) {
        int n = block0 + w * 4 + t;
        if (n >= n_nodes) return;
        int e0 = row_start[n];
        int e1 = row_start[n + 1];
        float idg = inv_deg[n];
        float4 s0 = {0,0,0,0}, s1 = {0,0,0,0}, s2 = {0,0,0,0}, s3 = {0,0,0,0};

        int e = e0 + h;
        for (; e + 6 < e1; e += 8) {
            int o0i = csr[e], o1i = csr[e + 2], o2i = csr[e + 4], o3i = csr[e + 6];
            float4 v0 = *(const float4*)(xbase + (size_t)(o0i + laneoff));
            float4 v1 = *(const float4*)(xbase + (size_t)(o1i + laneoff));
            float4 v2 = *(const float4*)(xbase + (size_t)(o2i + laneoff));
            float4 v3 = *(const float4*)(xbase + (size_t)(o3i + laneoff));
            s0.x += v0.x; s0.y += v0.y; s0.z += v0.z; s0.w += v0.w;
            s1.x += v1.x; s1.y += v1.y; s1.z += v1.z; s1.w += v1.w;
            s2.x += v2.x; s2.y += v2.y; s2.z += v2.z; s2.w += v2.w;
            s3.x += v3.x; s3.y += v3.y; s3.z += v3.z; s3.w += v3.w;
        }
        for (; e < e1; e += 2) {
            int o0i = csr[e];
            float4 v0 = *(const float4*)(xbase + (size_t)(o0i + laneoff));
            s0.x += v0.x; s0.y += v0.y; s0.z += v0.z; s0.w += v0.w;
        }

        float4 s;
        s.x = (s0.x + s1.x) + (s2.x + s3.x);
        s.y = (s0.y + s1.y) + (s2.y + s3.y);
        s.z = (s0.z + s1.z) + (s2.z + s3.z);
        s.w = (s0.w + s1.w) + (s2.w + s3.w);
        s.x += __shfl_down(s.x, 32);
        s.y += __shfl_down(s.y, 32);
        s.z += __shfl_down(s.z, 32);
        s.w += __shfl_down(s.w, 32);
        if (h == 0) {
            float4 r;
            r.x = s.x * idg; r.y = s.y * idg; r.z = s.z * idg; r.w = s.w * idg;
            ((float4*)(agg + (size_t)n * D))[sl] = r;
        }
    }
}

// ---------------- dual-GEMM + bias + relu kernel ----------------
// r7 tiling (32-node tile, thread = 4 nodes x 4 features, k-step 4, chained
// fmacs) + MANUAL weight double-buffer: next k-step's 8 weight float4s are
// loaded before the 128-fmac block and rotated at the bottom (r8 lesson: the
// compiler never pipelines VMEM on its own — it sank loads to the use point
// and stalled on vmcnt). #pragma unroll 2 renames the rotation (no v_movs).
// Weight buffers are padded by 4 k-rows so the k=124 prefetch stays in
// bounds. No launch_bounds: allocator takes ~110 VGPR for the double set
// (r3/r4: forced caps spill to scratch; spill tripwire = WRITE_SIZE).
#define FMA4(ACC, W, S) ACC.x += W.x * (S); ACC.y += W.y * (S); \
                        ACC.z += W.z * (S); ACC.w += W.w * (S);

__global__ void gemm_kernel(const float* __restrict__ agg, const float* __restrict__ xin,
                            float* __restrict__ xout,
                            const float* __restrict__ Wlt, const float* __restrict__ Wrt,
                            const float* __restrict__ bl, int n_nodes) {
    __shared__ __align__(16) float A[TG][D];
    __shared__ __align__(16) float X[TG][D];
    int tid = threadIdx.x;
    int block0 = blockIdx.x * TG;

    // stage 32 rows of agg and x (1024 float4 each -> 4 per thread each)
    const float4* agg4 = (const float4*)(agg + (size_t)block0 * D);
    const float4* x4   = (const float4*)(xin + (size_t)block0 * D);
    float4* A4 = (float4*)A;
    float4* X4 = (float4*)X;
    int limit4 = (n_nodes - block0) * 32;   // float4s available in this tile
    #pragma unroll
    for (int t = 0; t < 4; ++t) {
        int i = t * 256 + tid;
        float4 za = {0,0,0,0}, zx = {0,0,0,0};
        if (i < limit4) { za = agg4[i]; zx = x4[i]; }
        A4[i] = za;
        X4[i] = zx;
    }
    __syncthreads();

    int tf = tid & 31;      // feature float4 index
    int tn = tid >> 5;      // node group 0..7 -> nodes tn*4..tn*4+3
    int nbase = tn * 4;
    const float4* wlp = (const float4*)Wlt + tf;   // row k at wlp[k*32]
    const float4* wrp = (const float4*)Wrt + tf;
    float4 bv = ((const float4*)bl)[tf];
    float4 acc[4];
    #pragma unroll
    for (int i = 0; i < 4; ++i) acc[i] = bv;

    // preload k=0..3 weight rows
    float4 wl0 = wlp[0 * 32], wl1 = wlp[1 * 32], wl2 = wlp[2 * 32], wl3 = wlp[3 * 32];
    float4 wr0 = wrp[0 * 32], wr1 = wrp[1 * 32], wr2 = wrp[2 * 32], wr3 = wrp[3 * 32];

    #pragma unroll 2
    for (int k = 0; k < D; k += 4) {
        int kn = k + 4;   // padded rows make k=124 prefetch safe
        float4 nl0 = wlp[(kn + 0) * 32];
        float4 nl1 = wlp[(kn + 1) * 32];
        float4 nl2 = wlp[(kn + 2) * 32];
        float4 nl3 = wlp[(kn + 3) * 32];
        float4 nr0 = wrp[(kn + 0) * 32];
        float4 nr1 = wrp[(kn + 1) * 32];
        float4 nr2 = wrp[(kn + 2) * 32];
        float4 nr3 = wrp[(kn + 3) * 32];

        #pragma unroll
        for (int i = 0; i < 4; ++i) {
            float4 a  = *(const float4*)&A[nbase + i][k];
            float4 xx = *(const float4*)&X[nbase + i][k];
            FMA4(acc[i], wl0, a.x)  FMA4(acc[i], wl1, a.y)
            FMA4(acc[i], wl2, a.z)  FMA4(acc[i], wl3, a.w)
            FMA4(acc[i], wr0, xx.x) FMA4(acc[i], wr1, xx.y)
            FMA4(acc[i], wr2, xx.z) FMA4(acc[i], wr3, xx.w)
        }

        wl0 = nl0; wl1 = nl1; wl2 = nl2; wl3 = nl3;
        wr0 = nr0; wr1 = nr1; wr2 = nr2; wr3 = nr3;
    }

    #pragma unroll
    for (int i = 0; i < 4; ++i) {
        int n = block0 + nbase + i;
        if (n < n_nodes) {
            float4 r;
            r.x = fmaxf(acc[i].x, 0.f);
            r.y = fmaxf(acc[i].y, 0.f);
            r.z = fmaxf(acc[i].z, 0.f);
            r.w = fmaxf(acc[i].w, 0.f);
            ((float4*)xout)[(size_t)n * 32 + tf] = r;
        }
    }
}

extern "C" void kernel_launch(void* const* d_in, const int* in_sizes, int n_in,
                              void* d_out, int out_size, void* d_ws, size_t ws_size,
                              hipStream_t stream) {
    const float* x  = (const float*)d_in[0];
    const int*  edge = (const int*)d_in[1];
    const float* Wl = (const float*)d_in[2];
    const float* bl = (const float*)d_in[3];
    const float* Wr = (const float*)d_in[4];

    int N = in_sizes[0] / D;
    int E = in_sizes[1] / 2;
    int L = in_sizes[3] / D;
    const int* srcp = edge;
    const int* dstp = edge + E;

    char* w = (char*)d_ws;
    auto alloc = [&](size_t bytes) {
        char* p = w;
        w += (bytes + 255) & ~(size_t)255;
        return p;
    };
    int*   deg       = (int*)alloc((size_t)N * 4);
    int*   local_ex  = (int*)alloc((size_t)N * 4);
    int*   row_start = (int*)alloc((size_t)(N + 1) * 4);
    int*   cursor    = (int*)alloc((size_t)N * 4);
    int*   csr       = (int*)alloc((size_t)E * 4);
    float* invdeg    = (float*)alloc((size_t)N * 4);
    int*   blocksum  = (int*)alloc((size_t)1024 * 4);
    // +4 padded k-rows (4*D floats) so the gemm prefetch at k=124 of the
    // last layer reads valid memory.
    float* wlt       = (float*)alloc(((size_t)L * D * D + 4 * D) * 4);
    float* wrt       = (float*)alloc(((size_t)L * D * D + 4 * D) * 4);
    float* buf0      = (float*)alloc((size_t)N * D * 4);
    float* aggbuf    = (float*)alloc((size_t)N * D * 4);

    int nb1 = (N + 1023) / 1024;
    hipMemsetAsync(deg, 0, (size_t)N * 4, stream);
    hist_kernel<<<(E + 255) / 256, 256, 0, stream>>>(dstp, deg, E);
    scan1_kernel<<<nb1, 1024, 0, stream>>>(deg, local_ex, blocksum, N);
    scan2_kernel<<<1, 1024, 0, stream>>>(blocksum, nb1);
    scan3_kernel<<<nb1, 1024, 0, stream>>>(deg, local_ex, blocksum, row_start,
                                           cursor, invdeg, N, E);
    scatter_kernel<<<(E + 255) / 256, 256, 0, stream>>>(srcp, dstp, cursor, csr, E);
    int tw = L * D * D;
    transpose_w<<<(tw + 255) / 256, 256, 0, stream>>>(Wl, Wr, wlt, wrt, tw);

    float* out = (float*)d_out;
    const float* cur = x;
    int nb_agg  = (N + TM - 1) / TM;
    int nb_gemm = (N + TG - 1) / TG;
    for (int l = 0; l < L; ++l) {
        float* o = (l & 1) ? out : buf0;
        if (l == L - 1) o = out;
        agg_kernel<<<nb_agg, 256, 0, stream>>>(cur, aggbuf, row_start, csr, invdeg, N);
        gemm_kernel<<<nb_gemm, 256, 0, stream>>>(aggbuf, cur, o,
                                                 wlt + (size_t)l * D * D,
                                                 wrt + (size_t)l * D * D,
                                                 bl + (size_t)l * D, N);
        cur = o;
    }
}

// Round 10
// 1294.449 us; speedup vs baseline: 1.1963x; 1.0380x over previous
//
#include <hip/hip_runtime.h>

#define D 128
#define TM 16   // fused layer tile: 16 nodes, 16 KB LDS -> 8 blocks/CU

// ---------------- CSR build ----------------

__global__ void hist_kernel(const int* __restrict__ dst, int* __restrict__ deg, int E) {
    int i = blockIdx.x * blockDim.x + threadIdx.x;
    if (i < E) atomicAdd(&deg[dst[i]], 1);
}

__global__ void scan1_kernel(const int* __restrict__ deg, int* __restrict__ local_excl,
                             int* __restrict__ blocksum, int n) {
    __shared__ int tmp[1024];
    int i = blockIdx.x * 1024 + threadIdx.x;
    int v = (i < n) ? deg[i] : 0;
    tmp[threadIdx.x] = v;
    __syncthreads();
    for (int off = 1; off < 1024; off <<= 1) {
        int t = 0;
        if (threadIdx.x >= off) t = tmp[threadIdx.x - off];
        __syncthreads();
        if (threadIdx.x >= off) tmp[threadIdx.x] += t;
        __syncthreads();
    }
    int incl = tmp[threadIdx.x];
    if (i < n) local_excl[i] = incl - v;
    if (threadIdx.x == 1023) blocksum[blockIdx.x] = tmp[1023];
}

__global__ void scan2_kernel(int* __restrict__ blocksum, int nb) {
    __shared__ int tmp[1024];
    int v = (threadIdx.x < nb) ? blocksum[threadIdx.x] : 0;
    tmp[threadIdx.x] = v;
    __syncthreads();
    for (int off = 1; off < 1024; off <<= 1) {
        int t = 0;
        if (threadIdx.x >= off) t = tmp[threadIdx.x - off];
        __syncthreads();
        if (threadIdx.x >= off) tmp[threadIdx.x] += t;
        __syncthreads();
    }
    if (threadIdx.x < nb) blocksum[threadIdx.x] = tmp[threadIdx.x] - v;  // exclusive
}

__global__ void scan3_kernel(const int* __restrict__ deg, const int* __restrict__ local_excl,
                             const int* __restrict__ blocksum, int* __restrict__ row_start,
                             int* __restrict__ cursor, float* __restrict__ inv_deg,
                             int n, int n_edges) {
    int i = blockIdx.x * 1024 + threadIdx.x;
    if (i < n) {
        int rs = local_excl[i] + blocksum[blockIdx.x];
        row_start[i] = rs;
        cursor[i]    = rs;
        inv_deg[i]   = 1.0f / fmaxf((float)deg[i], 1.0f);
    }
    if (i == 0) row_start[n] = n_edges;
}

// csr[] holds BYTE offsets of the source row (src * D * 4).
__global__ void scatter_kernel(const int* __restrict__ src, const int* __restrict__ dst,
                               int* __restrict__ cursor, int* __restrict__ csr, int E) {
    int i = blockIdx.x * blockDim.x + threadIdx.x;
    if (i < E) {
        int d = dst[i];
        int p = atomicAdd(&cursor[d], 1);
        csr[p] = src[i] << 9;   // * 512 bytes per row
    }
}

// ---------------- weight transpose (W[l][f][k] -> Wt[l][k][f]) ----------------

__global__ void transpose_w(const float* __restrict__ Wl, const float* __restrict__ Wr,
                            float* __restrict__ Wlt, float* __restrict__ Wrt, int total) {
    int i = blockIdx.x * blockDim.x + threadIdx.x;
    if (i < total) {
        int l = i >> 14;
        int r = i & 16383;
        int f = r >> 7;
        int k = r & 127;
        int o = (l << 14) + (k << 7) + f;
        Wlt[o] = Wl[i];
        Wrt[o] = Wr[i];
    }
}

// ---------------- fused SAGE layer ----------------
// r2's proven gather (8 loads in flight/wave) + r7's chained-fmac GEMM,
// 16-node tile. Rationale (r7-r9 lesson): the compiler will not hold
// prefetched VMEM registers (manual dbuf -> VGPR 52, sunk loads), so ILP
// can't be forced from source; the robust lever is TLP. 16 KB LDS + ~60
// VGPR allows up to 8 blocks/CU (32 waves) vs 3 blocks at the r7 32-node
// tile — enough waves to cover each iteration's vmcnt stall. Fusion also
// removes the aggbuf 100 MB/layer round-trip and 4 launches.
#define FMA4(ACC, W, S) ACC.x += W.x * (S); ACC.y += W.y * (S); \
                        ACC.z += W.z * (S); ACC.w += W.w * (S);

__global__ void sage_layer(const float* __restrict__ xin, float* __restrict__ xout,
                           const int* __restrict__ row_start, const int* __restrict__ csr,
                           const float* __restrict__ inv_deg,
                           const float* __restrict__ Wlt, const float* __restrict__ Wrt,
                           const float* __restrict__ bl, int n_nodes) {
    __shared__ __align__(16) float A[TM][D];
    __shared__ __align__(16) float X[TM][D];
    int block0 = blockIdx.x * TM;
    int tid = threadIdx.x;

    // Phase A: one wave per node (4 nodes/wave sequentially). Two 32-lane
    // halves walk alternate edges with a 4-deep float4 pipeline each ->
    // 8 row loads in flight per wave. All threads reach the barrier.
    {
        int lane = tid & 63;
        int w    = tid >> 6;      // wave 0..3
        int h    = lane >> 5;     // half 0/1
        int sl   = lane & 31;     // sub-lane within half
        const char* xbase = (const char*)xin;
        int laneoff = sl * 16;

        for (int t = 0; t < 4; ++t) {
            int j = w * 4 + t;
            int n = block0 + j;
            float4 s0 = {0,0,0,0}, s1 = {0,0,0,0}, s2 = {0,0,0,0}, s3 = {0,0,0,0};
            float idg = 1.f;
            float2 xv = {0.f, 0.f};
            int e0 = 0, e1 = 0;
            if (n < n_nodes) {
                e0 = row_start[n];
                e1 = row_start[n + 1];
                idg = inv_deg[n];
                xv = ((const float2*)(xin + (size_t)n * D))[lane];
            }
            ((float2*)X[j])[lane] = xv;

            int e = e0 + h;
            for (; e + 6 < e1; e += 8) {
                int o0i = csr[e], o1i = csr[e + 2], o2i = csr[e + 4], o3i = csr[e + 6];
                float4 v0 = *(const float4*)(xbase + (size_t)(o0i + laneoff));
                float4 v1 = *(const float4*)(xbase + (size_t)(o1i + laneoff));
                float4 v2 = *(const float4*)(xbase + (size_t)(o2i + laneoff));
                float4 v3 = *(const float4*)(xbase + (size_t)(o3i + laneoff));
                s0.x += v0.x; s0.y += v0.y; s0.z += v0.z; s0.w += v0.w;
                s1.x += v1.x; s1.y += v1.y; s1.z += v1.z; s1.w += v1.w;
                s2.x += v2.x; s2.y += v2.y; s2.z += v2.z; s2.w += v2.w;
                s3.x += v3.x; s3.y += v3.y; s3.z += v3.z; s3.w += v3.w;
            }
            for (; e < e1; e += 2) {
                int o0i = csr[e];
                float4 v0 = *(const float4*)(xbase + (size_t)(o0i + laneoff));
                s0.x += v0.x; s0.y += v0.y; s0.z += v0.z; s0.w += v0.w;
            }

            float4 s;
            s.x = (s0.x + s1.x) + (s2.x + s3.x);
            s.y = (s0.y + s1.y) + (s2.y + s3.y);
            s.z = (s0.z + s1.z) + (s2.z + s3.z);
            s.w = (s0.w + s1.w) + (s2.w + s3.w);
            s.x += __shfl_down(s.x, 32);
            s.y += __shfl_down(s.y, 32);
            s.z += __shfl_down(s.z, 32);
            s.w += __shfl_down(s.w, 32);
            if (h == 0) {
                float4 r;
                r.x = s.x * idg; r.y = s.y * idg; r.z = s.z * idg; r.w = s.w * idg;
                ((float4*)A[j])[sl] = r;
            }
        }
    }
    __syncthreads();

    // Phase B: thread = 2 nodes x 4 features, k-step 4, chained fmacs
    // (r6 lesson: chained single-product += contracts to v_fmac_f32).
    int tf = tid & 31;      // feature float4 index
    int tn = tid >> 5;      // 0..7 -> nodes tn*2, tn*2+1
    int j0 = tn * 2, j1 = j0 + 1;
    const float4* wlp = (const float4*)Wlt + tf;   // row k at wlp[k*32]
    const float4* wrp = (const float4*)Wrt + tf;
    float4 bv = ((const float4*)bl)[tf];
    float4 acc0 = bv, acc1 = bv;
    const float* Arow0 = A[j0];
    const float* Arow1 = A[j1];
    const float* Xrow0 = X[j0];
    const float* Xrow1 = X[j1];

    for (int k = 0; k < D; k += 4) {
        float4 wl0 = wlp[(k + 0) * 32];
        float4 wl1 = wlp[(k + 1) * 32];
        float4 wl2 = wlp[(k + 2) * 32];
        float4 wl3 = wlp[(k + 3) * 32];
        float4 wr0 = wrp[(k + 0) * 32];
        float4 wr1 = wrp[(k + 1) * 32];
        float4 wr2 = wrp[(k + 2) * 32];
        float4 wr3 = wrp[(k + 3) * 32];
        float4 a0 = *(const float4*)&Arow0[k];
        float4 a1 = *(const float4*)&Arow1[k];
        float4 x0 = *(const float4*)&Xrow0[k];
        float4 x1 = *(const float4*)&Xrow1[k];

        FMA4(acc0, wl0, a0.x) FMA4(acc0, wl1, a0.y)
        FMA4(acc0, wl2, a0.z) FMA4(acc0, wl3, a0.w)
        FMA4(acc0, wr0, x0.x) FMA4(acc0, wr1, x0.y)
        FMA4(acc0, wr2, x0.z) FMA4(acc0, wr3, x0.w)
        FMA4(acc1, wl0, a1.x) FMA4(acc1, wl1, a1.y)
        FMA4(acc1, wl2, a1.z) FMA4(acc1, wl3, a1.w)
        FMA4(acc1, wr0, x1.x) FMA4(acc1, wr1, x1.y)
        FMA4(acc1, wr2, x1.z) FMA4(acc1, wr3, x1.w)
    }

    int n0 = block0 + j0, n1 = block0 + j1;
    if (n0 < n_nodes) {
        float4 r;
        r.x = fmaxf(acc0.x, 0.f); r.y = fmaxf(acc0.y, 0.f);
        r.z = fmaxf(acc0.z, 0.f); r.w = fmaxf(acc0.w, 0.f);
        ((float4*)xout)[(size_t)n0 * 32 + tf] = r;
    }
    if (n1 < n_nodes) {
        float4 r;
        r.x = fmaxf(acc1.x, 0.f); r.y = fmaxf(acc1.y, 0.f);
        r.z = fmaxf(acc1.z, 0.f); r.w = fmaxf(acc1.w, 0.f);
        ((float4*)xout)[(size_t)n1 * 32 + tf] = r;
    }
}

extern "C" void kernel_launch(void* const* d_in, const int* in_sizes, int n_in,
                              void* d_out, int out_size, void* d_ws, size_t ws_size,
                              hipStream_t stream) {
    const float* x  = (const float*)d_in[0];
    const int*  edge = (const int*)d_in[1];
    const float* Wl = (const float*)d_in[2];
    const float* bl = (const float*)d_in[3];
    const float* Wr = (const float*)d_in[4];

    int N = in_sizes[0] / D;
    int E = in_sizes[1] / 2;
    int L = in_sizes[3] / D;
    const int* srcp = edge;
    const int* dstp = edge + E;

    char* w = (char*)d_ws;
    auto alloc = [&](size_t bytes) {
        char* p = w;
        w += (bytes + 255) & ~(size_t)255;
        return p;
    };
    int*   deg       = (int*)alloc((size_t)N * 4);
    int*   local_ex  = (int*)alloc((size_t)N * 4);
    int*   row_start = (int*)alloc((size_t)(N + 1) * 4);
    int*   cursor    = (int*)alloc((size_t)N * 4);
    int*   csr       = (int*)alloc((size_t)E * 4);
    float* invdeg    = (float*)alloc((size_t)N * 4);
    int*   blocksum  = (int*)alloc((size_t)1024 * 4);
    float* wlt       = (float*)alloc((size_t)L * D * D * 4);
    float* wrt       = (float*)alloc((size_t)L * D * D * 4);
    float* buf0      = (float*)alloc((size_t)N * D * 4);

    int nb1 = (N + 1023) / 1024;
    hipMemsetAsync(deg, 0, (size_t)N * 4, stream);
    hist_kernel<<<(E + 255) / 256, 256, 0, stream>>>(dstp, deg, E);
    scan1_kernel<<<nb1, 1024, 0, stream>>>(deg, local_ex, blocksum, N);
    scan2_kernel<<<1, 1024, 0, stream>>>(blocksum, nb1);
    scan3_kernel<<<nb1, 1024, 0, stream>>>(deg, local_ex, blocksum, row_start,
                                           cursor, invdeg, N, E);
    scatter_kernel<<<(E + 255) / 256, 256, 0, stream>>>(srcp, dstp, cursor, csr, E);
    int tw = L * D * D;
    transpose_w<<<(tw + 255) / 256, 256, 0, stream>>>(Wl, Wr, wlt, wrt, tw);

    float* out = (float*)d_out;
    const float* cur = x;
    int nbl = (N + TM - 1) / TM;
    for (int l = 0; l < L; ++l) {
        float* o = (l & 1) ? out : buf0;
        if (l == L - 1) o = out;
        sage_layer<<<nbl, 256, 0, stream>>>(cur, o, row_start, csr, invdeg,
                                            wlt + (size_t)l * D * D,
                                            wrt + (size_t)l * D * D,
                                            bl + (size_t)l * D, N);
        cur = o;
    }
}